// Round 6
// baseline (606.395 us; speedup 1.0000x reference)
//
#include <hip/hip_runtime.h>

#define NPROJ 180
#define PHALF 90
#define DH 192
#define DW 384
#define VN 96
#define ZPER 4
#define TCOLS 65                     // u0l in [2,60] -> u0l+1 <= 64 in-window (r7-proven)
#define TPAD 1024                    // 4x256 unguarded staging; tail rows benign in-detector
#define PSTRIDE (DH * DW)
#define BSTRIDE (NPROJ * DH * DW)

typedef float v2f __attribute__((ext_vector_type(2)));

// no-drain barrier: drain own LDS writes (lgkmcnt only), then sync. Global
// prefetch loads stay IN FLIGHT across the barrier; __syncthreads() would
// emit s_waitcnt vmcnt(0) here (gfx950 barrier drain) and stall every proj.
#define BAR() asm volatile("s_waitcnt lgkmcnt(0)\n\ts_barrier" ::: "memory")

// r15 = r14 with the macro-pasting bug fixed (G##0.x pasted gA with the
// pp-number "0.x" -> invalid token; now the 4 register names are passed
// explicitly, no token pasting). Logic identical to r14's intent:
//  - r10's proven structure (65-col batch-interleaved tile, double buffer,
//    one barrier/proj, 2-half split, 186us champion)
//  - BAR(): lgkmcnt-only drain; depth-2 prefetch (gA/gB) issued ~2 proj
//    phases before its ds_write's counted vmcnt wait
//  - all prefetch state in named scalars: no address-taken arrays, nothing
//    for the asm "memory" clobber to flush (r13's 582MB scratch bug)
#define ISSUE(Ga, Gb, Gc, Gd, p, cu_, cv_) do {                               \
    const char* b0_ = (const char*)(sino + (size_t)(p) * PSTRIDE              \
                                    + (cv_) * DW + (cu_));                    \
    const char* b1_ = b0_ + (size_t)BSTRIDE * 4;                              \
    Ga.x = *(const float*)(b0_ + VgB0); Ga.y = *(const float*)(b1_ + VgB0);   \
    Gb.x = *(const float*)(b0_ + VgB1); Gb.y = *(const float*)(b1_ + VgB1);   \
    Gc.x = *(const float*)(b0_ + VgB2); Gc.y = *(const float*)(b1_ + VgB2);   \
    Gd.x = *(const float*)(b0_ + VgB3); Gd.y = *(const float*)(b1_ + VgB3);   \
} while (0)

#define STAGE(buf, Ga, Gb, Gc, Gd) do {                                       \
    (buf)[tid]       = Ga;                                                    \
    (buf)[tid + 256] = Gb;                                                    \
    (buf)[tid + 512] = Gc;                                                    \
    (buf)[tid + 768] = Gd;                                                    \
} while (0)

__global__ __launch_bounds__(256, 6) void cone_bp(
    const float* __restrict__ sino,   // [B, P, H, W]
    const float* __restrict__ mats,   // [P, 3, 4]
    float* __restrict__ out)          // [B, Z, Y, X]
{
    __shared__ v2f tile[2][TPAD];     // 16 KB
    __shared__ int2 anch[PHALF];      // 720 B anchor table

    const int tid = threadIdx.x;
    // 8x8 per-wave lane map (r7-proven)
    const int x = blockIdx.x * 32 + ((tid & 7) | ((tid >> 6) << 3));
    const int y = blockIdx.y * 8 + ((tid >> 3) & 7);
    const int half = (blockIdx.z >= 24) ? 1 : 0;
    const int zc = blockIdx.z - 24 * half;
    const int pbase = half * PHALF;

    const float xw = (float)x - 47.5f;
    const float yw = (float)y - 47.5f;
    const float zw0 = (float)(zc * ZPER) - 47.5f;

    // block-center world coords (tile anchoring)
    const float xwc = (float)(blockIdx.x * 32) - 32.0f;
    const float ywc = (float)(blockIdx.y * 8) - 44.0f;
    const float zwc = (float)(zc * ZPER) - 46.0f;

    const float4* __restrict__ M = (const float4*)mats;

    // ---- anchor table: one projection per thread, once ----
    if (tid < PHALF) {
        int p = pbase + tid;
        float4 a0 = M[p * 3 + 0];
        float4 a1 = M[p * 3 + 1];
        float4 a2 = M[p * 3 + 2];
        float unc = fmaf(a0.x, xwc, fmaf(a0.y, ywc, a0.w));
        float vnc = fmaf(a1.x, xwc, fmaf(a1.y, ywc, fmaf(a1.z, zwc, a1.w)));
        float wc  = fmaf(a2.x, xwc, fmaf(a2.y, ywc, a2.w));
        float rwc = __builtin_amdgcn_rcpf(wc);
        anch[tid] = make_int2((int)floorf(unc * rwc) - 31,
                              (int)floorf(vnc * rwc) - 6);
    }

    // ---- staging map: loop-invariant BYTE offsets (named scalars) ----
    int VgB0, VgB1, VgB2, VgB3;
    {
        int li, row, col;
        li = tid;        row = li / TCOLS; col = li - row * TCOLS; VgB0 = (row * DW + col) * 4;
        li = tid + 256;  row = li / TCOLS; col = li - row * TCOLS; VgB1 = (row * DW + col) * 4;
        li = tid + 512;  row = li / TCOLS; col = li - row * TCOLS; VgB2 = (row * DW + col) * 4;
        li = tid + 768;  row = li / TCOLS; col = li - row * TCOLS; VgB3 = (row * DW + col) * 4;
    }

    __syncthreads();    // anchor table ready (once; full drain fine here)

    // ---- depth-2 prologue: gA <- proj 0, gB <- proj 1 ----
    v2f gA0, gA1, gA2, gA3, gB0, gB1, gB2, gB3;
    int cu, cv;
    {
        int2 a = anch[0];
        cu = __builtin_amdgcn_readfirstlane(a.x);
        cv = __builtin_amdgcn_readfirstlane(a.y);
    }
    ISSUE(gA0, gA1, gA2, gA3, pbase, cu, cv);
    float nfuA = -(float)cu, nfvA = -(float)cv;
    {
        int2 a = anch[1];
        cu = __builtin_amdgcn_readfirstlane(a.x);
        cv = __builtin_amdgcn_readfirstlane(a.y);
    }
    ISSUE(gB0, gB1, gB2, gB3, pbase + 1, cu, cv);
    float nfuB = -(float)cu, nfvB = -(float)cv;

    v2f acc[ZPER];
#pragma unroll
    for (int k = 0; k < ZPER; ++k) acc[k] = (v2f)(0.0f);

    auto sample = [&](int i, const v2f* buf, float nfu, float nfv) {
        const int p = pbase + i;
        float4 r0 = M[p * 3 + 0];
        float4 r1 = M[p * 3 + 1];
        float4 r2 = M[p * 3 + 2];
        float un  = fmaf(r0.x, xw, fmaf(r0.y, yw, r0.w));
        float vn0 = fmaf(r1.x, xw, fmaf(r1.y, yw, r1.w));
        float w   = fmaf(r2.x, xw, fmaf(r2.y, yw, r2.w));
        float rw  = __builtin_amdgcn_rcpf(w);
        float iw2 = rw * rw;                         // FDK 1/w^2
        float ul  = fmaf(un, rw, nfu);               // tile-local u (z-indep)
        float uf  = floorf(ul);
        float fu  = ul - uf;
        int   u0l = (int)uf;
        float vb  = fmaf(fmaf(r1.z, zw0, vn0), rw, nfv);
        float dv  = r1.z * rw;

        // phase 1: entry offsets + fv
        int   o[ZPER];
        float fv[ZPER];
#pragma unroll
        for (int k = 0; k < ZPER; ++k) {
            float v  = fmaf(dv, (float)k, vb);
            float vf = floorf(v);
            fv[k] = v - vf;
            o[k] = (int)vf * TCOLS + u0l;
        }
        // phase 2: all LDS reads (mergeable ds_read2_b64)
        v2f E00[ZPER], E01[ZPER], E10[ZPER], E11[ZPER];
#pragma unroll
        for (int k = 0; k < ZPER; ++k) {
            E00[k] = buf[o[k]];
            E01[k] = buf[o[k] + 1];
            E10[k] = buf[o[k] + TCOLS];
            E11[k] = buf[o[k] + TCOLS + 1];
        }
        // phase 3: fully packed bilinear + accumulate
#pragma unroll
        for (int k = 0; k < ZPER; ++k) {
            v2f F0 = E00[k] + (E10[k] - E00[k]) * fv[k];
            v2f F1 = E01[k] + (E11[k] - E01[k]) * fv[k];
            v2f H  = F0 + (F1 - F0) * fu;
            acc[k] += H * iw2;
        }
    };

    for (int i = 0; i < PHALF; i += 2) {
        // ---- proj i: tile[0] <- gA (counted vmcnt); prefetch i+2 -> gA ----
        {
            STAGE(tile[0], gA0, gA1, gA2, gA3);
            const float su = nfuA, sv = nfvA;
            if (i + 2 < PHALF) {
                int2 a = anch[i + 2];
                cu = __builtin_amdgcn_readfirstlane(a.x);
                cv = __builtin_amdgcn_readfirstlane(a.y);
                ISSUE(gA0, gA1, gA2, gA3, pbase + i + 2, cu, cv);
                nfuA = -(float)cu; nfvA = -(float)cv;
            }
            BAR();                                // lgkm drain only; vmem flies
            sample(i, tile[0], su, sv);
        }
        // ---- proj i+1: tile[1] <- gB; prefetch i+3 -> gB ----
        {
            STAGE(tile[1], gB0, gB1, gB2, gB3);
            const float su = nfuB, sv = nfvB;
            if (i + 3 < PHALF) {
                int2 a = anch[i + 3];
                cu = __builtin_amdgcn_readfirstlane(a.x);
                cv = __builtin_amdgcn_readfirstlane(a.y);
                ISSUE(gB0, gB1, gB2, gB3, pbase + i + 3, cu, cv);
                nfuB = -(float)cu; nfvB = -(float)cv;
            }
            BAR();
            sample(i + 1, tile[1], su, sv);
        }
    }

    // ---- merge: exactly 2 blocks per voxel -> order-independent fp32 add ----
    const int zbase = zc * ZPER;
#pragma unroll
    for (int k = 0; k < ZPER; ++k) {
        unsafeAtomicAdd(&out[(((size_t)(zbase + k)) * VN + y) * VN + x],
                        acc[k].x);
        unsafeAtomicAdd(&out[(((size_t)(VN + zbase + k)) * VN + y) * VN + x],
                        acc[k].y);
    }
}

extern "C" void kernel_launch(void* const* d_in, const int* in_sizes, int n_in,
                              void* d_out, int out_size, void* d_ws, size_t ws_size,
                              hipStream_t stream) {
    const float* sino = (const float*)d_in[0];   // [2,180,192,384,1] fp32
    const float* mats = (const float*)d_in[1];   // [180,3,4] fp32
    float* out = (float*)d_out;                  // [2,96,96,96,1] fp32

    // d_out is poisoned before every launch; atomic merge needs zeros
    hipMemsetAsync(out, 0, (size_t)out_size * sizeof(float), stream);

    // grid: 3 x-tiles, 12 y-tiles, 24 z-chunks x 2 projection halves
    dim3 grid(VN / 32, VN / 8, 48), block(256);
    hipLaunchKernelGGL(cone_bp, grid, block, 0, stream, sino, mats, out);
}

// Round 7
// 301.277 us; speedup vs baseline: 2.0128x; 2.0128x over previous
//
#include <hip/hip_runtime.h>

#define NPROJ 180
#define PHALF 90
#define DH 192
#define DW 384
#define VN 96
#define ZPER 4
#define TCOLS 65                     // u0l in [2,60] -> u0l+1 <= 64 in-window (r7-proven)
#define TPAD 1024                    // 4x256 unguarded staging; tail rows benign in-detector
#define PSTRIDE (DH * DW)
#define BSTRIDE (NPROJ * DH * DW)

typedef float v2f __attribute__((ext_vector_type(2)));

// r16 = r10 (186us champion) with ONE change: the per-projection
// __syncthreads() is replaced by an LDS-only fence + raw barrier, all
// compiler-modeled intrinsics (ZERO inline asm -- r13/r15 proved that an
// asm-volatile barrier with "memory" clobber makes hipcc demote loop state
// to scratch: 581 MB writes, SGPR 48->32, identical counters across two
// different implementations).
//   release-fence(workgroup, local): s_waitcnt lgkmcnt(0) -- own ds_writes
//     visible CU-wide; NO vmcnt drain.
//   s_barrier; acquire-fence(local): free on gfx9 (LDS coherent).
// Effect: the global prefetch loads for proj i+1 (issued before the
// barrier, r10 placement) stay IN FLIGHT across it and are consumed by the
// compiler's COUNTED vmcnt before the next phase's ds_write (T4 pattern) --
// removing the per-projection vmcnt(0) barrier drain that __syncthreads()
// emits (the m97-documented stall, ~40% of r10's runtime).
// Safety: fences order all LDS ops at IR level; phase-i readers' ds_reads
// drain at phase-i+1's release fence, two fences before tile[b]'s next
// writer -- r10's double-buffer invariant verbatim.
#define BARRIER_LDS() do {                                          \
    __builtin_amdgcn_fence(__ATOMIC_RELEASE, "workgroup", "local"); \
    __builtin_amdgcn_s_barrier();                                   \
    __builtin_amdgcn_fence(__ATOMIC_ACQUIRE, "workgroup", "local"); \
} while (0)

__global__ __launch_bounds__(256, 6) void cone_bp(
    const float* __restrict__ sino,   // [B, P, H, W]
    const float* __restrict__ mats,   // [P, 3, 4]
    float* __restrict__ out)          // [B, Z, Y, X]
{
    __shared__ v2f tile[2][TPAD];     // 16 KB
    __shared__ int2 anch[PHALF];      // 720 B anchor table

    const int tid = threadIdx.x;
    // 8x8 per-wave lane map (r7-proven)
    const int x = blockIdx.x * 32 + ((tid & 7) | ((tid >> 6) << 3));
    const int y = blockIdx.y * 8 + ((tid >> 3) & 7);
    const int half = (blockIdx.z >= 24) ? 1 : 0;
    const int zc = blockIdx.z - 24 * half;
    const int pbase = half * PHALF;

    const float xw = (float)x - 47.5f;
    const float yw = (float)y - 47.5f;
    const float zw0 = (float)(zc * ZPER) - 47.5f;

    // block-center world coords (tile anchoring)
    const float xwc = (float)(blockIdx.x * 32) - 32.0f;
    const float ywc = (float)(blockIdx.y * 8) - 44.0f;
    const float zwc = (float)(zc * ZPER) - 46.0f;

    const float4* __restrict__ M = (const float4*)mats;

    // ---- anchor table: one projection per thread, once ----
    if (tid < PHALF) {
        int p = pbase + tid;
        float4 a0 = M[p * 3 + 0];
        float4 a1 = M[p * 3 + 1];
        float4 a2 = M[p * 3 + 2];
        float unc = fmaf(a0.x, xwc, fmaf(a0.y, ywc, a0.w));
        float vnc = fmaf(a1.x, xwc, fmaf(a1.y, ywc, fmaf(a1.z, zwc, a1.w)));
        float wc  = fmaf(a2.x, xwc, fmaf(a2.y, ywc, a2.w));
        float rwc = __builtin_amdgcn_rcpf(wc);
        anch[tid] = make_int2((int)floorf(unc * rwc) - 31,
                              (int)floorf(vnc * rwc) - 6);
    }

    // ---- staging map: loop-invariant BYTE offsets within a projection ----
    int VgB[4];
#pragma unroll
    for (int k = 0; k < 4; ++k) {
        int li = tid + 256 * k;
        int row = li / TCOLS;
        int col = li - row * TCOLS;
        VgB[k] = (row * DW + col) * 4;
    }

    __syncthreads();    // anchor table ready (once; full drain fine here)

    // ---- preload first projection into registers ----
    int cu, cv;         // anchor of the projection currently in g[]
    {
        int2 a = anch[0];
        cu = __builtin_amdgcn_readfirstlane(a.x);
        cv = __builtin_amdgcn_readfirstlane(a.y);
    }
    v2f g[4];
    {
        const char* p0 = (const char*)(sino + pbase * PSTRIDE + cv * DW + cu);
        const char* p1 = p0 + (size_t)BSTRIDE * 4;
#pragma unroll
        for (int k = 0; k < 4; ++k) {
            g[k].x = *(const float*)(p0 + VgB[k]);
            g[k].y = *(const float*)(p1 + VgB[k]);
        }
    }

    v2f acc[ZPER];
#pragma unroll
    for (int k = 0; k < ZPER; ++k) acc[k] = (v2f)(0.0f);

    auto body = [&](int i, v2f* __restrict__ buf) {
        // ---- stage proj i (in g) into buf; counted vmcnt wait on g ----
#pragma unroll
        for (int k = 0; k < 4; ++k)
            buf[tid + 256 * k] = g[k];
        const float nfu = -(float)cu;        // sampling anchor (this proj)
        const float nfv = -(float)cv;

        // ---- issue p+1 staging loads BEFORE barrier (fly across it) ----
        if (i + 1 < PHALF) {
            int2 a = anch[i + 1];
            cu = __builtin_amdgcn_readfirstlane(a.x);
            cv = __builtin_amdgcn_readfirstlane(a.y);
            const char* p0 = (const char*)(sino
                + (pbase + i + 1) * PSTRIDE + cv * DW + cu);
            const char* p1 = p0 + (size_t)BSTRIDE * 4;
#pragma unroll
            for (int k = 0; k < 4; ++k) {
                g[k].x = *(const float*)(p0 + VgB[k]);
                g[k].y = *(const float*)(p1 + VgB[k]);
            }
        }

        BARRIER_LDS();     // lgkm drain + barrier; prefetch stays in flight

        // ---- sample projection pbase+i (both batches packed in v2f) ----
        const int p = pbase + i;
        float4 r0 = M[p * 3 + 0];
        float4 r1 = M[p * 3 + 1];
        float4 r2 = M[p * 3 + 2];
        float un  = fmaf(r0.x, xw, fmaf(r0.y, yw, r0.w));
        float vn0 = fmaf(r1.x, xw, fmaf(r1.y, yw, r1.w));
        float w   = fmaf(r2.x, xw, fmaf(r2.y, yw, r2.w));
        float rw  = __builtin_amdgcn_rcpf(w);
        float iw2 = rw * rw;                         // FDK 1/w^2
        float ul  = fmaf(un, rw, nfu);               // tile-local u (z-indep)
        float uf  = floorf(ul);
        float fu  = ul - uf;
        int   u0l = (int)uf;
        float vb  = fmaf(fmaf(r1.z, zw0, vn0), rw, nfv);
        float dv  = r1.z * rw;

        // phase 1: entry offsets + fv
        int   o[ZPER];
        float fv[ZPER];
#pragma unroll
        for (int k = 0; k < ZPER; ++k) {
            float v  = fmaf(dv, (float)k, vb);
            float vf = floorf(v);
            fv[k] = v - vf;
            o[k] = (int)vf * TCOLS + u0l;
        }
        // phase 2: all LDS reads (mergeable ds_read2_b64)
        v2f E00[ZPER], E01[ZPER], E10[ZPER], E11[ZPER];
#pragma unroll
        for (int k = 0; k < ZPER; ++k) {
            E00[k] = buf[o[k]];
            E01[k] = buf[o[k] + 1];
            E10[k] = buf[o[k] + TCOLS];
            E11[k] = buf[o[k] + TCOLS + 1];
        }
        // phase 3: fully packed bilinear + accumulate
#pragma unroll
        for (int k = 0; k < ZPER; ++k) {
            v2f F0 = E00[k] + (E10[k] - E00[k]) * fv[k];
            v2f F1 = E01[k] + (E11[k] - E01[k]) * fv[k];
            v2f H  = F0 + (F1 - F0) * fu;
            acc[k] += H * iw2;
        }
    };

    // unrolled-by-2 so the buffer parity is a compile-time imm offset
    for (int i = 0; i < PHALF; i += 2) {
        body(i,     tile[0]);
        body(i + 1, tile[1]);
    }

    // ---- merge: exactly 2 blocks per voxel -> order-independent fp32 add ----
    const int zbase = zc * ZPER;
#pragma unroll
    for (int k = 0; k < ZPER; ++k) {
        unsafeAtomicAdd(&out[(((size_t)(zbase + k)) * VN + y) * VN + x],
                        acc[k].x);
        unsafeAtomicAdd(&out[(((size_t)(VN + zbase + k)) * VN + y) * VN + x],
                        acc[k].y);
    }
}

extern "C" void kernel_launch(void* const* d_in, const int* in_sizes, int n_in,
                              void* d_out, int out_size, void* d_ws, size_t ws_size,
                              hipStream_t stream) {
    const float* sino = (const float*)d_in[0];   // [2,180,192,384,1] fp32
    const float* mats = (const float*)d_in[1];   // [180,3,4] fp32
    float* out = (float*)d_out;                  // [2,96,96,96,1] fp32

    // d_out is poisoned before every launch; atomic merge needs zeros
    hipMemsetAsync(out, 0, (size_t)out_size * sizeof(float), stream);

    // grid: 3 x-tiles, 12 y-tiles, 24 z-chunks x 2 projection halves
    dim3 grid(VN / 32, VN / 8, 48), block(256);
    hipLaunchKernelGGL(cone_bp, grid, block, 0, stream, sino, mats, out);
}

// Round 8
// 298.871 us; speedup vs baseline: 2.0290x; 1.0080x over previous
//
#include <hip/hip_runtime.h>

#define NPROJ 180
#define DH 192
#define DW 384
#define VN 96
#define ZPER 4
#define ZCH (VN / ZPER)              // 24 z-chunks
#define TCOLS 65                     // u0l in [2,60] -> u0l+1 <= 64 in-window (r7-proven)
#define TPAD 1024                    // 4x256 unguarded staging; tail rows benign in-detector
#define PSTRIDE (DH * DW)
#define BSTRIDE (NPROJ * DH * DW)

typedef float v2f __attribute__((ext_vector_type(2)));

// LDS-only barrier (r16-proven, zero inline asm): release-fence(local) =
// lgkmcnt(0) drain, s_barrier, acquire-fence(local) free. Global prefetch
// loads stay in flight across it; compiler emits counted vmcnt before the
// next ds_write of the prefetched registers.
#define BARRIER_LDS() do {                                          \
    __builtin_amdgcn_fence(__ATOMIC_RELEASE, "workgroup", "local"); \
    __builtin_amdgcn_s_barrier();                                   \
    __builtin_amdgcn_fence(__ATOMIC_ACQUIRE, "workgroup", "local"); \
} while (0)

// r17: TLP experiment. Theory chain: not VALU (r11), not barrier count
// (r11), not vmcnt drain (r16), not conflicts (9%/CU) -> latency-bound at
// 47% occupancy with only 6.75 blocks/CU of work. Fix: 4 projection
// quarters (45 each) x ZPER=4 -> grid 3456 blocks = 13.5 blocks/CU work,
// 8 resident (LDS 17.4KB, VGPR 40, launch_bounds(256,8)). Total staging
// traffic invariant. Merge: quarters {0,1}->out, {2,3}->ws (exactly 2
// order-free atomic addends per buffer; r11-proven), then out += ws.
// Fallback to 2-half variant (grid 1728) if ws too small.
template<int PQ, int NQ>
__global__ __launch_bounds__(256, 8) void cone_bp(
    const float* __restrict__ sino,   // [B, P, H, W]
    const float* __restrict__ mats,   // [P, 3, 4]
    float* __restrict__ out,          // [B, Z, Y, X]
    float* __restrict__ ws)           // quarters 2,3 (NQ=4 only)
{
    __shared__ v2f tile[2][TPAD];     // 16 KB
    __shared__ int2 anch[PQ];         // anchor table

    const int tid = threadIdx.x;
    // 8x8 per-wave lane map (r7-proven)
    const int x = blockIdx.x * 32 + ((tid & 7) | ((tid >> 6) << 3));
    const int y = blockIdx.y * 8 + ((tid >> 3) & 7);
    const int zc = blockIdx.z % ZCH;
    const int qt = blockIdx.z / ZCH;
    const int pbase = qt * PQ;

    const float xw = (float)x - 47.5f;
    const float yw = (float)y - 47.5f;
    const float zw0 = (float)(zc * ZPER) - 47.5f;

    // block-center world coords (tile anchoring)
    const float xwc = (float)(blockIdx.x * 32) - 32.0f;
    const float ywc = (float)(blockIdx.y * 8) - 44.0f;
    const float zwc = (float)(zc * ZPER) - 46.0f;

    const float4* __restrict__ M = (const float4*)mats;

    // ---- anchor table: one projection per thread, once ----
    if (tid < PQ) {
        int p = pbase + tid;
        float4 a0 = M[p * 3 + 0];
        float4 a1 = M[p * 3 + 1];
        float4 a2 = M[p * 3 + 2];
        float unc = fmaf(a0.x, xwc, fmaf(a0.y, ywc, a0.w));
        float vnc = fmaf(a1.x, xwc, fmaf(a1.y, ywc, fmaf(a1.z, zwc, a1.w)));
        float wc  = fmaf(a2.x, xwc, fmaf(a2.y, ywc, a2.w));
        float rwc = __builtin_amdgcn_rcpf(wc);
        anch[tid] = make_int2((int)floorf(unc * rwc) - 31,
                              (int)floorf(vnc * rwc) - 6);
    }

    // ---- staging map: loop-invariant BYTE offsets within a projection ----
    int VgB[4];
#pragma unroll
    for (int k = 0; k < 4; ++k) {
        int li = tid + 256 * k;
        int row = li / TCOLS;
        int col = li - row * TCOLS;
        VgB[k] = (row * DW + col) * 4;
    }

    __syncthreads();    // anchor table ready (once; full drain fine here)

    // ---- preload first projection into registers ----
    int cu, cv;         // anchor of the projection currently in g[]
    {
        int2 a = anch[0];
        cu = __builtin_amdgcn_readfirstlane(a.x);
        cv = __builtin_amdgcn_readfirstlane(a.y);
    }
    v2f g[4];
    {
        const char* p0 = (const char*)(sino + pbase * PSTRIDE + cv * DW + cu);
        const char* p1 = p0 + (size_t)BSTRIDE * 4;
#pragma unroll
        for (int k = 0; k < 4; ++k) {
            g[k].x = *(const float*)(p0 + VgB[k]);
            g[k].y = *(const float*)(p1 + VgB[k]);
        }
    }

    v2f acc[ZPER];
#pragma unroll
    for (int k = 0; k < ZPER; ++k) acc[k] = (v2f)(0.0f);

    auto body = [&](int i, v2f* __restrict__ buf) {
        // ---- stage proj i (in g) into buf; counted vmcnt wait on g ----
#pragma unroll
        for (int k = 0; k < 4; ++k)
            buf[tid + 256 * k] = g[k];
        const float nfu = -(float)cu;        // sampling anchor (this proj)
        const float nfv = -(float)cv;

        // ---- issue p+1 staging loads BEFORE barrier (fly across it) ----
        if (i + 1 < PQ) {
            int2 a = anch[i + 1];
            cu = __builtin_amdgcn_readfirstlane(a.x);
            cv = __builtin_amdgcn_readfirstlane(a.y);
            const char* p0 = (const char*)(sino
                + (pbase + i + 1) * PSTRIDE + cv * DW + cu);
            const char* p1 = p0 + (size_t)BSTRIDE * 4;
#pragma unroll
            for (int k = 0; k < 4; ++k) {
                g[k].x = *(const float*)(p0 + VgB[k]);
                g[k].y = *(const float*)(p1 + VgB[k]);
            }
        }

        BARRIER_LDS();     // lgkm drain + barrier; prefetch stays in flight

        // ---- sample projection pbase+i (both batches packed in v2f) ----
        const int p = pbase + i;
        float4 r0 = M[p * 3 + 0];
        float4 r1 = M[p * 3 + 1];
        float4 r2 = M[p * 3 + 2];
        float un  = fmaf(r0.x, xw, fmaf(r0.y, yw, r0.w));
        float vn0 = fmaf(r1.x, xw, fmaf(r1.y, yw, r1.w));
        float w   = fmaf(r2.x, xw, fmaf(r2.y, yw, r2.w));
        float rw  = __builtin_amdgcn_rcpf(w);
        float iw2 = rw * rw;                         // FDK 1/w^2
        float ul  = fmaf(un, rw, nfu);               // tile-local u (z-indep)
        float uf  = floorf(ul);
        float fu  = ul - uf;
        int   u0l = (int)uf;
        float vb  = fmaf(fmaf(r1.z, zw0, vn0), rw, nfv);
        float dv  = r1.z * rw;

        // phase 1: entry offsets + fv
        int   o[ZPER];
        float fv[ZPER];
#pragma unroll
        for (int k = 0; k < ZPER; ++k) {
            float v  = fmaf(dv, (float)k, vb);
            float vf = floorf(v);
            fv[k] = v - vf;
            o[k] = (int)vf * TCOLS + u0l;
        }
        // phase 2: all LDS reads (mergeable ds_read2_b64)
        v2f E00[ZPER], E01[ZPER], E10[ZPER], E11[ZPER];
#pragma unroll
        for (int k = 0; k < ZPER; ++k) {
            E00[k] = buf[o[k]];
            E01[k] = buf[o[k] + 1];
            E10[k] = buf[o[k] + TCOLS];
            E11[k] = buf[o[k] + TCOLS + 1];
        }
        // phase 3: fully packed bilinear + accumulate
#pragma unroll
        for (int k = 0; k < ZPER; ++k) {
            v2f F0 = E00[k] + (E10[k] - E00[k]) * fv[k];
            v2f F1 = E01[k] + (E11[k] - E01[k]) * fv[k];
            v2f H  = F0 + (F1 - F0) * fu;
            acc[k] += H * iw2;
        }
    };

    // unrolled-by-2 so the buffer parity is a compile-time imm offset
    for (int i = 0; i < PQ; i += 2) {
        body(i, tile[0]);
        if (i + 1 < PQ) body(i + 1, tile[1]);
    }

    // ---- merge: exactly 2 atomic addends per voxel per buffer ----
    float* __restrict__ dst = (NQ == 4 && qt >= 2) ? ws : out;
    const int zbase = zc * ZPER;
#pragma unroll
    for (int k = 0; k < ZPER; ++k) {
        unsafeAtomicAdd(&dst[(((size_t)(zbase + k)) * VN + y) * VN + x],
                        acc[k].x);
        unsafeAtomicAdd(&dst[(((size_t)(VN + zbase + k)) * VN + y) * VN + x],
                        acc[k].y);
    }
}

// out += ws, float4-vectorized (2*96^3 floats = 442368 float4)
__global__ __launch_bounds__(256) void add_ws(
    float4* __restrict__ out, const float4* __restrict__ ws, int n4)
{
    int i = blockIdx.x * 256 + threadIdx.x;
    if (i < n4) {
        float4 a = ws[i];
        float4 b = out[i];
        b.x += a.x; b.y += a.y; b.z += a.z; b.w += a.w;
        out[i] = b;
    }
}

extern "C" void kernel_launch(void* const* d_in, const int* in_sizes, int n_in,
                              void* d_out, int out_size, void* d_ws, size_t ws_size,
                              hipStream_t stream) {
    const float* sino = (const float*)d_in[0];   // [2,180,192,384,1] fp32
    const float* mats = (const float*)d_in[1];   // [180,3,4] fp32
    float* out = (float*)d_out;                  // [2,96,96,96,1] fp32
    float* wsf = (float*)d_ws;

    const size_t nvox = (size_t)2 * VN * VN * VN;           // 1769472
    // d_out is poisoned before every launch; atomic merge needs zeros
    hipMemsetAsync(out, 0, (size_t)out_size * sizeof(float), stream);

    if (ws_size >= nvox * sizeof(float)) {
        // 4 projection-quarters: grid 3 x 12 x (24 z-chunks * 4 quarters)
        hipMemsetAsync(wsf, 0, nvox * sizeof(float), stream);
        dim3 grid(VN / 32, VN / 8, ZCH * 4), block(256);
        hipLaunchKernelGGL((cone_bp<NPROJ / 4, 4>), grid, block, 0, stream,
                           sino, mats, out, wsf);
        int n4 = (int)(nvox / 4);
        hipLaunchKernelGGL(add_ws, dim3((n4 + 255) / 256), block, 0, stream,
                           (float4*)out, (const float4*)wsf, n4);
    } else {
        // fallback: 2 halves (r16 geometry), no workspace
        dim3 grid(VN / 32, VN / 8, ZCH * 2), block(256);
        hipLaunchKernelGGL((cone_bp<NPROJ / 2, 2>), grid, block, 0, stream,
                           sino, mats, out, (float*)nullptr);
    }
}